// Round 16
// baseline (67.776 us; speedup 1.0000x reference)
//
#include <hip/hip_runtime.h>
#include <hip/hip_bf16.h>

#define N_NODES 131072
#define BATCH 128
#define H 256
#define TROWS 32
#define TPB 8                  // tiles per persistent block
#define GRID 512               // 512 * 8 * 32 = 131072 rows

typedef _Float16 half8 __attribute__((ext_vector_type(8)));
typedef float floatx4 __attribute__((ext_vector_type(4)));

// ---------------------------------------------------------------------------
// Prep: blocks 0..31 pack W1 into MFMA fragment order (f16); blocks 32..159
// zero pacc (128*256); block 32 also zeros pz (128). Runs every call so the
// atomic accumulators start from zero on each graph replay.
// ---------------------------------------------------------------------------
__global__ __launch_bounds__(256) void prep_kernel(
    const float* __restrict__ W1, _Float16* __restrict__ W1p,
    float* __restrict__ pacc, float* __restrict__ pz)
{
    const int bid = blockIdx.x;
    const int tid = threadIdx.x;
    if (bid < 32) {
        const int g = bid * 256 + tid;          // [0, 8192)
        const int ct = g >> 9;
        const int ks = (g >> 6) & 7;
        const int l  = g & 63;
        const int k0 = ks * 32 + (l >> 4) * 8;
        const int col = ct * 16 + (l & 15);
        half8 h;
        #pragma unroll
        for (int j = 0; j < 8; ++j) h[j] = (_Float16)W1[(k0 + j) * H + col];
        reinterpret_cast<half8*>(W1p)[g] = h;
    } else {
        pacc[(bid - 32) * 256 + tid] = 0.f;     // 128*256 = 32768 exactly
        if (bid == 32 && tid < BATCH) pz[tid] = 0.f;
    }
}

// ---------------------------------------------------------------------------
// FUSED persistent kernel (r15 lesson: occupancy/barriers are NOT the
// limiter; the exposed L2 latency of in-loop B loads is the chain).
//   - B (W1p) fragments: ALL 32 half8 held in registers for the whole
//     kernel (128 VGPR). Loaded from L2 exactly once per wave.
//   - Persistent: each block processes TPB=8 consecutive 32-row tiles.
//     GRID=512 -> 2 blocks/CU (VGPR ~230, __launch_bounds__(256,2)).
//   - X staging: register prefetch (issue tile t+1's 8 dwordx4 during
//     compute of t) + DOUBLE-BUFFERED 2x16KB LDS -> HBM latency and
//     stage-writes never sit on the serial chain.
//   - MFMA phase is LDS-only; PV column-partitioned, barrier-lean,
//     coalesced per-wave atomics (r15 verified form).
// sp/scL single-buffered: their tile-(t+1) writes happen after barrier-A
// of t+1, which all waves reach only after finishing PV(t). Safe.
// Max-free softmax (|score| <= ||W2||_1+|b2| ~ 13, exp f32-safe).
// ---------------------------------------------------------------------------
__global__ __launch_bounds__(256, 2) void fused_kernel(
    const float* __restrict__ X, const _Float16* __restrict__ W1p,
    const float* __restrict__ b1, const float* __restrict__ W2,
    const float* __restrict__ b2, const int* __restrict__ offsets,
    float* __restrict__ pacc, float* __restrict__ pz)
{
    __shared__ __align__(16) _Float16 Xs[2][TROWS * H];   // 2 x 16 KB, swizzled
    __shared__ float sp[4][TROWS];
    __shared__ float scL[TROWS];
    __shared__ int offL[BATCH];

    const int tid = threadIdx.x;
    const int wave = tid >> 6;
    const int lane = tid & 63;

    // XCD-chunked bijective swizzle (512 % 8 == 0)
    const int bid = (int)(blockIdx.x & 7) * (GRID / 8) + (int)(blockIdx.x >> 3);
    const int tile0 = bid * TPB;

    if (tid < BATCH) offL[tid] = offsets[tid];

    // ---- hoist ALL B fragments into registers (once per kernel) ----
    const half8* Bw = reinterpret_cast<const half8*>(W1p) + wave * 2048 + lane;
    half8 B0[8], B1[8], B2[8], B3[8];
    #pragma unroll
    for (int ks = 0; ks < 8; ++ks) {
        B0[ks] = Bw[ks * 64];
        B1[ks] = Bw[512 + ks * 64];
        B2[ks] = Bw[1024 + ks * 64];
        B3[ks] = Bw[1536 + ks * 64];
    }

    float w2v[4], b1v[4];
    #pragma unroll
    for (int ctl = 0; ctl < 4; ++ctl) {
        const int col = wave * 64 + ctl * 16 + (lane & 15);
        w2v[ctl] = W2[col];
        b1v[ctl] = b1[col];
    }
    const float bias2 = b2[0];

    const float4* X4 = reinterpret_cast<const float4*>(X);

    // staging registers (tile t+1 in flight while computing tile t)
    float4 va[4], vb[4];
    {
        const float4* Xv = X4 + (long long)tile0 * TROWS * 64;
        #pragma unroll
        for (int i = 0; i < 4; ++i) {
            const int c = tid + i * 256;
            const int row = c >> 5;
            const int col8 = c & 31;
            va[i] = Xv[row * 64 + col8 * 2];
            vb[i] = Xv[row * 64 + col8 * 2 + 1];
        }
    }

    for (int t = 0; t < TPB; ++t) {
        const int t0 = (tile0 + t) * TROWS;
        char* Xb = reinterpret_cast<char*>(&Xs[t & 1][0]);

        // ---- 1. cvt staged regs -> swizzled LDS buffer (t&1) ----
        #pragma unroll
        for (int i = 0; i < 4; ++i) {
            const int c = tid + i * 256;
            const int row = c >> 5;
            const int col8 = c & 31;
            half8 h;
            h[0] = (_Float16)va[i].x; h[1] = (_Float16)va[i].y;
            h[2] = (_Float16)va[i].z; h[3] = (_Float16)va[i].w;
            h[4] = (_Float16)vb[i].x; h[5] = (_Float16)vb[i].y;
            h[6] = (_Float16)vb[i].z; h[7] = (_Float16)vb[i].w;
            const int byte = row * 512 + (col8 * 16 ^ ((row & 7) << 4));
            *reinterpret_cast<half8*>(Xb + byte) = h;
        }
        // ---- 2. issue next tile's loads (latency hides under 3-5) ----
        if (t < TPB - 1) {
            const float4* Xv = X4 + (long long)(tile0 + t + 1) * TROWS * 64;
            #pragma unroll
            for (int i = 0; i < 4; ++i) {
                const int c = tid + i * 256;
                const int row = c >> 5;
                const int col8 = c & 31;
                va[i] = Xv[row * 64 + col8 * 2];
                vb[i] = Xv[row * 64 + col8 * 2 + 1];
            }
        }
        __syncthreads();   // [A] Xs[t&1] ready (t=0: offL too)

        // ---- 3. MFMA (LDS + registers only) ----
        floatx4 acc[2][4];
        #pragma unroll
        for (int rt = 0; rt < 2; ++rt)
            #pragma unroll
            for (int ctl = 0; ctl < 4; ++ctl)
                acc[rt][ctl] = (floatx4){0.f, 0.f, 0.f, 0.f};

        #pragma unroll
        for (int ks = 0; ks < 8; ++ks) {
            half8 af[2];
            #pragma unroll
            for (int rt = 0; rt < 2; ++rt) {
                const int row = rt * 16 + (lane & 15);
                const int byte = row * 512 +
                    ((ks * 64 + (lane >> 4) * 16) ^ ((row & 7) << 4));
                af[rt] = *reinterpret_cast<const half8*>(Xb + byte);
            }
            #pragma unroll
            for (int rt = 0; rt < 2; ++rt) {
                acc[rt][0] = __builtin_amdgcn_mfma_f32_16x16x32_f16(af[rt], B0[ks], acc[rt][0], 0, 0, 0);
                acc[rt][1] = __builtin_amdgcn_mfma_f32_16x16x32_f16(af[rt], B1[ks], acc[rt][1], 0, 0, 0);
                acc[rt][2] = __builtin_amdgcn_mfma_f32_16x16x32_f16(af[rt], B2[ks], acc[rt][2], 0, 0, 0);
                acc[rt][3] = __builtin_amdgcn_mfma_f32_16x16x32_f16(af[rt], B3[ks], acc[rt][3], 0, 0, 0);
            }
        }

        // ---- 4. epilogue: tanh + W2 dot -> 16-lane reduce -> sp -> exp ----
        float sc[2][4];
        #pragma unroll
        for (int rt = 0; rt < 2; ++rt) {
            #pragma unroll
            for (int reg = 0; reg < 4; ++reg) {
                float s = 0.f;
                #pragma unroll
                for (int ctl = 0; ctl < 4; ++ctl) {
                    const float x = acc[rt][ctl][reg] + b1v[ctl];
                    const float tt = 1.f - 2.f / (__expf(2.f * x) + 1.f);
                    s = fmaf(tt, w2v[ctl], s);
                }
                sc[rt][reg] = s;
            }
        }
        #pragma unroll
        for (int off = 1; off < 16; off <<= 1)
            #pragma unroll
            for (int rt = 0; rt < 2; ++rt)
                #pragma unroll
                for (int reg = 0; reg < 4; ++reg)
                    sc[rt][reg] += __shfl_xor(sc[rt][reg], off);

        if ((lane & 15) == 0) {
            #pragma unroll
            for (int rt = 0; rt < 2; ++rt)
                #pragma unroll
                for (int reg = 0; reg < 4; ++reg)
                    sp[wave][rt * 16 + (lane >> 4) * 4 + reg] = sc[rt][reg];
        }
        __syncthreads();   // [B] sp ready
        if (tid < TROWS)
            scL[tid] = __expf(sp[0][tid] + sp[1][tid] + sp[2][tid] + sp[3][tid] + bias2);
        __syncthreads();   // [C] scL ready

        // ---- 5. PV, column-partitioned, barrier-free, coalesced atomics ----
        int g_lo, g_hi;
        {
            int node = t0;
            if (node < offL[0]) g_lo = -1;
            else {
                int lo = 0, hi = BATCH - 1;
                while (lo < hi) { int mid = (lo + hi + 1) >> 1; if (offL[mid] <= node) lo = mid; else hi = mid - 1; }
                g_lo = lo;
            }
            node = t0 + TROWS - 1;
            if (node < offL[0]) g_hi = -1;
            else {
                int lo = 0, hi = BATCH - 1;
                while (lo < hi) { int mid = (lo + hi + 1) >> 1; if (offL[mid] <= node) lo = mid; else hi = mid - 1; }
                g_hi = lo;
            }
        }

        const int cbase = (8 * wave + (lane >> 3)) << 4;   // 16B-chunk byte of col
        const int woff = (lane & 7) * 2;                   // within-chunk byte

        for (int g = (g_lo < 0 ? 0 : g_lo); g <= g_hi; ++g) {
            const int rs = max(t0, offL[g]);
            const int re = min(t0 + TROWS, (g == BATCH - 1) ? N_NODES : offL[g + 1]);

            float a = 0.f, z = 0.f;
            for (int i = rs; i < re; ++i) {
                const int r = i - t0;
                const float p = scL[r];
                const int byte = r * 512 + (cbase ^ ((r & 7) << 4)) + woff;
                a = fmaf(p, (float)*reinterpret_cast<const _Float16*>(Xb + byte), a);
                z += p;
            }
            atomicAdd(&pacc[g * H + wave * 64 + lane], a);   // 64 consecutive floats
            if (tid == 0) atomicAdd(&pz[g], z);
        }
        __syncthreads();   // [D] PV(t) done before cvt-write of t+1 epoch's sp
    }
}

// ---------------------------------------------------------------------------
// Reduce: segment b = union of gaps [max(b-1,0), min(b+1,127)].
// out = sum(acc_g) / sum(z_g). 128 blocks x 256 threads.
// ---------------------------------------------------------------------------
__global__ __launch_bounds__(256) void reduce_kernel(
    const float* __restrict__ pacc, const float* __restrict__ pz,
    float* __restrict__ out)
{
    const int b = blockIdx.x;
    const int tid = threadIdx.x;
    const int g0 = (b == 0) ? 0 : b - 1;
    const int g1 = (b >= BATCH - 1) ? BATCH - 1 : b + 1;

    float r = 0.f, z = 0.f;
    for (int g = g0; g <= g1; ++g) {
        r += pacc[g * H + tid];
        z += pz[g];
    }
    out[b * H + tid] = r / z;
}

// ---------------------------------------------------------------------------
extern "C" void kernel_launch(void* const* d_in, const int* in_sizes, int n_in,
                              void* d_out, int out_size, void* d_ws, size_t ws_size,
                              hipStream_t stream)
{
    const float* X     = (const float*)d_in[0];
    const int* offs    = (const int*)d_in[1];   // int64 in ref -> int32 on device
    const float* W1    = (const float*)d_in[2];
    const float* b1    = (const float*)d_in[3];
    const float* W2    = (const float*)d_in[4];
    const float* b2    = (const float*)d_in[5];
    float* out         = (float*)d_out;

    // workspace layout (floats):
    //   [0, 32768)        pacc   (128 gaps x 256)
    //   [32768, 32896)    pz     (128)
    //   [32896, ...)      W1p    (65536 f16 = 128 KB)
    float* pacc   = (float*)d_ws;
    float* pz     = pacc + BATCH * H;
    _Float16* W1p = (_Float16*)(pz + BATCH);

    prep_kernel<<<160, 256, 0, stream>>>(W1, W1p, pacc, pz);
    fused_kernel<<<GRID, 256, 0, stream>>>(X, W1p, b1, W2, b2, offs, pacc, pz);
    reduce_kernel<<<BATCH, 256, 0, stream>>>(pacc, pz, out);
}

// Round 17
// 67.521 us; speedup vs baseline: 1.0038x; 1.0038x over previous
//
#include <hip/hip_runtime.h>
#include <hip/hip_bf16.h>

#define N_NODES 131072
#define BATCH 128
#define H 256
#define TROWS 32
#define NTILES (N_NODES / TROWS)   // 4096 tiles of 32 rows

typedef _Float16 half8 __attribute__((ext_vector_type(8)));
typedef float floatx4 __attribute__((ext_vector_type(4)));

typedef __attribute__((address_space(3))) void lds_void_t;
typedef __attribute__((address_space(1))) const void gbl_void_t;

// ---------------------------------------------------------------------------
// Prep: blocks 0..31 pack W1 into MFMA fragment order (f16); blocks 32..159
// zero pacc (128*256); block 32 also zeros pz (128). Runs every call so the
// atomic accumulators start from zero on each graph replay.
// ---------------------------------------------------------------------------
__global__ __launch_bounds__(256) void prep_kernel(
    const float* __restrict__ W1, _Float16* __restrict__ W1p,
    float* __restrict__ pacc, float* __restrict__ pz)
{
    const int bid = blockIdx.x;
    const int tid = threadIdx.x;
    if (bid < 32) {
        const int g = bid * 256 + tid;          // [0, 8192)
        const int ct = g >> 9;
        const int ks = (g >> 6) & 7;
        const int l  = g & 63;
        const int k0 = ks * 32 + (l >> 4) * 8;
        const int col = ct * 16 + (l & 15);
        half8 h;
        #pragma unroll
        for (int j = 0; j < 8; ++j) h[j] = (_Float16)W1[(k0 + j) * H + col];
        reinterpret_cast<half8*>(W1p)[g] = h;
    } else {
        pacc[(bid - 32) * 256 + tid] = 0.f;     // 128*256 = 32768 exactly
        if (bid == 32 && tid < BATCH) pz[tid] = 0.f;
    }
}

// ---------------------------------------------------------------------------
// FUSED kernel = r14 structure (best known, 61.0us) with ONE change:
// X staged f32 via global_load_lds (direct-to-LDS DMA, width=16), with
// source-side chunk-XOR pre-swizzle (linear LDS dest + inverse-swizzled
// global source + same XOR on every read — rule 21 pattern).
//   - LDS chunk l of row r holds global chunk (l ^ (r&7)); readers of
//     global chunk c fetch LDS chunk (c ^ (r&7)).
//   - MFMA A-fragments: 2x ds_read_b128 (f32) + cvt to f16 at load.
//   - PV: float4 f32 read per row (one chunk per lane).
// Max-free softmax (|score| <= ||W2||_1+|b2| ~ 13, exp f32-safe).
// ---------------------------------------------------------------------------
__global__ __launch_bounds__(256, 4) void fused_kernel(
    const float* __restrict__ X, const _Float16* __restrict__ W1p,
    const float* __restrict__ b1, const float* __restrict__ W2,
    const float* __restrict__ b2, const int* __restrict__ offsets,
    float* __restrict__ pacc, float* __restrict__ pz)
{
    __shared__ __align__(16) float Xsf[TROWS * H];   // 32 KB f32, src-swizzled
    __shared__ float sp[4][TROWS];
    __shared__ float scL[TROWS];
    __shared__ float accL[4][H];
    __shared__ float zLs[4];
    __shared__ int offL[BATCH];

    const int tid = threadIdx.x;
    const int wave = tid >> 6;
    const int lane = tid & 63;

    // XCD-chunked bijective swizzle (4096 % 8 == 0)
    const int bid = (int)(blockIdx.x & 7) * (NTILES / 8) + (int)(blockIdx.x >> 3);
    const int t0 = bid * TROWS;

    if (tid < BATCH) offL[tid] = offsets[tid];

    // ---- 1. stage X tile: 8 global_load_lds per wave (1 row = 1 KB each),
    //         global source chunk pre-swizzled by (row & 7) ----
    {
        #pragma unroll
        for (int i = 0; i < 8; ++i) {
            const int r = wave * 8 + i;
            const float* g = X + ((long long)(t0 + r) << 8) + ((lane ^ (r & 7)) << 2);
            __builtin_amdgcn_global_load_lds((gbl_void_t*)g,
                                             (lds_void_t*)&Xsf[r * 256], 16, 0, 0);
        }
    }
    __syncthreads();   // [barrier 1] vmcnt(0) drained; Xs + offL ready

    const float4* Xf4 = reinterpret_cast<const float4*>(Xsf);   // 64 chunks/row

    // ---- 2. MFMA: wave w = col-tiles [4w,4w+4), rows = 2 row-tiles ----
    floatx4 acc[2][4];
    #pragma unroll
    for (int rt = 0; rt < 2; ++rt)
        #pragma unroll
        for (int ctl = 0; ctl < 4; ++ctl)
            acc[rt][ctl] = (floatx4){0.f, 0.f, 0.f, 0.f};

    const half8* Bw = reinterpret_cast<const half8*>(W1p) + wave * 2048 + lane;

    #pragma unroll 1
    for (int ks = 0; ks < 8; ++ks) {
        half8 bf0 = Bw[ks * 64];
        half8 bf1 = Bw[512 + ks * 64];
        half8 bf2 = Bw[1024 + ks * 64];
        half8 bf3 = Bw[1536 + ks * 64];
        half8 af[2];
        #pragma unroll
        for (int rt = 0; rt < 2; ++rt) {
            const int row = rt * 16 + (lane & 15);
            const int s = row & 7;
            const int c0 = ks * 8 + (lane >> 4) * 2;   // global chunk of 8 cols
            float4 x0 = Xf4[row * 64 + (c0 ^ s)];
            float4 x1 = Xf4[row * 64 + ((c0 + 1) ^ s)];
            half8 h;
            h[0] = (_Float16)x0.x; h[1] = (_Float16)x0.y;
            h[2] = (_Float16)x0.z; h[3] = (_Float16)x0.w;
            h[4] = (_Float16)x1.x; h[5] = (_Float16)x1.y;
            h[6] = (_Float16)x1.z; h[7] = (_Float16)x1.w;
            af[rt] = h;
        }
        #pragma unroll
        for (int rt = 0; rt < 2; ++rt) {
            acc[rt][0] = __builtin_amdgcn_mfma_f32_16x16x32_f16(af[rt], bf0, acc[rt][0], 0, 0, 0);
            acc[rt][1] = __builtin_amdgcn_mfma_f32_16x16x32_f16(af[rt], bf1, acc[rt][1], 0, 0, 0);
            acc[rt][2] = __builtin_amdgcn_mfma_f32_16x16x32_f16(af[rt], bf2, acc[rt][2], 0, 0, 0);
            acc[rt][3] = __builtin_amdgcn_mfma_f32_16x16x32_f16(af[rt], bf3, acc[rt][3], 0, 0, 0);
        }
    }

    // ---- 3. epilogue: tanh + W2 dot -> 16-lane reduce -> sp -> exp ----
    float w2v[4], b1v[4];
    #pragma unroll
    for (int ctl = 0; ctl < 4; ++ctl) {
        const int col = wave * 64 + ctl * 16 + (lane & 15);
        w2v[ctl] = W2[col];
        b1v[ctl] = b1[col];
    }

    float sc[2][4];
    #pragma unroll
    for (int rt = 0; rt < 2; ++rt) {
        #pragma unroll
        for (int reg = 0; reg < 4; ++reg) {
            float s = 0.f;
            #pragma unroll
            for (int ctl = 0; ctl < 4; ++ctl) {
                const float x = acc[rt][ctl][reg] + b1v[ctl];
                const float t = 1.f - 2.f / (__expf(2.f * x) + 1.f);
                s = fmaf(t, w2v[ctl], s);
            }
            sc[rt][reg] = s;
        }
    }
    #pragma unroll
    for (int off = 1; off < 16; off <<= 1)
        #pragma unroll
        for (int rt = 0; rt < 2; ++rt)
            #pragma unroll
            for (int reg = 0; reg < 4; ++reg)
                sc[rt][reg] += __shfl_xor(sc[rt][reg], off);

    if ((lane & 15) == 0) {
        #pragma unroll
        for (int rt = 0; rt < 2; ++rt)
            #pragma unroll
            for (int reg = 0; reg < 4; ++reg)
                sp[wave][rt * 16 + (lane >> 4) * 4 + reg] = sc[rt][reg];
    }
    __syncthreads();   // [barrier 2] sp ready
    if (tid < TROWS)
        scL[tid] = __expf(sp[0][tid] + sp[1][tid] + sp[2][tid] + sp[3][tid] + b2[0]);
    __syncthreads();   // [barrier 3] scL ready

    // ---- 4. PV from LDS (f32); accL combine; per-block atomics per gap ----
    int g_lo, g_hi;
    {
        int node = t0;
        if (node < offL[0]) g_lo = -1;
        else {
            int lo = 0, hi = BATCH - 1;
            while (lo < hi) { int mid = (lo + hi + 1) >> 1; if (offL[mid] <= node) lo = mid; else hi = mid - 1; }
            g_lo = lo;
        }
        node = t0 + TROWS - 1;
        if (node < offL[0]) g_hi = -1;
        else {
            int lo = 0, hi = BATCH - 1;
            while (lo < hi) { int mid = (lo + hi + 1) >> 1; if (offL[mid] <= node) lo = mid; else hi = mid - 1; }
            g_hi = lo;
        }
    }

    for (int g = (g_lo < 0 ? 0 : g_lo); g <= g_hi; ++g) {
        const int rs = max(t0, offL[g]);
        const int re = min(t0 + TROWS, (g == BATCH - 1) ? N_NODES : offL[g + 1]);

        float4 a4 = {0.f, 0.f, 0.f, 0.f};
        float z = 0.f;
        for (int i = rs + wave; i < re; i += 4) {
            const int r = i - t0;
            const float p = scL[r];
            float4 xv = Xf4[r * 64 + (lane ^ (r & 7))];   // lane's 4 cols, f32
            a4.x = fmaf(p, xv.x, a4.x);
            a4.y = fmaf(p, xv.y, a4.y);
            a4.z = fmaf(p, xv.z, a4.z);
            a4.w = fmaf(p, xv.w, a4.w);
            z += p;
        }
        reinterpret_cast<float4*>(&accL[wave][0])[lane] = a4;
        if (lane == 0) zLs[wave] = z;
        __syncthreads();
        const float v = accL[0][tid] + accL[1][tid] + accL[2][tid] + accL[3][tid];
        atomicAdd(&pacc[g * H + tid], v);
        if (tid == 0) atomicAdd(&pz[g], zLs[0] + zLs[1] + zLs[2] + zLs[3]);
        __syncthreads();   // accL reused by next gap
    }
}

// ---------------------------------------------------------------------------
// Reduce: segment b = union of gaps [max(b-1,0), min(b+1,127)].
// out = sum(acc_g) / sum(z_g). 128 blocks x 256 threads.
// ---------------------------------------------------------------------------
__global__ __launch_bounds__(256) void reduce_kernel(
    const float* __restrict__ pacc, const float* __restrict__ pz,
    float* __restrict__ out)
{
    const int b = blockIdx.x;
    const int tid = threadIdx.x;
    const int g0 = (b == 0) ? 0 : b - 1;
    const int g1 = (b >= BATCH - 1) ? BATCH - 1 : b + 1;

    float r = 0.f, z = 0.f;
    for (int g = g0; g <= g1; ++g) {
        r += pacc[g * H + tid];
        z += pz[g];
    }
    out[b * H + tid] = r / z;
}

// ---------------------------------------------------------------------------
extern "C" void kernel_launch(void* const* d_in, const int* in_sizes, int n_in,
                              void* d_out, int out_size, void* d_ws, size_t ws_size,
                              hipStream_t stream)
{
    const float* X     = (const float*)d_in[0];
    const int* offs    = (const int*)d_in[1];   // int64 in ref -> int32 on device
    const float* W1    = (const float*)d_in[2];
    const float* b1    = (const float*)d_in[3];
    const float* W2    = (const float*)d_in[4];
    const float* b2    = (const float*)d_in[5];
    float* out         = (float*)d_out;

    // workspace layout (floats):
    //   [0, 32768)        pacc   (128 gaps x 256)
    //   [32768, 32896)    pz     (128)
    //   [32896, ...)      W1p    (65536 f16 = 128 KB)
    float* pacc   = (float*)d_ws;
    float* pz     = pacc + BATCH * H;
    _Float16* W1p = (_Float16*)(pz + BATCH);

    prep_kernel<<<160, 256, 0, stream>>>(W1, W1p, pacc, pz);
    fused_kernel<<<NTILES, 256, 0, stream>>>(X, W1p, b1, W2, b2, offs, pacc, pz);
    reduce_kernel<<<BATCH, 256, 0, stream>>>(pacc, pz, out);
}

// Round 18
// 65.197 us; speedup vs baseline: 1.0396x; 1.0357x over previous
//
#include <hip/hip_runtime.h>
#include <hip/hip_bf16.h>

#define N_NODES 131072
#define BATCH 128
#define TROWS 32
#define H 256
#define NBLOCKS (N_NODES / 64)   // 2048 blocks, 2 x 32-row tiles each

typedef _Float16 half8 __attribute__((ext_vector_type(8)));
typedef _Float16 half4 __attribute__((ext_vector_type(4)));
typedef float floatx4 __attribute__((ext_vector_type(4)));

// ---------------------------------------------------------------------------
// Prep: blocks 0..31 pack W1 into MFMA fragment order (f16); blocks 32..159
// zero pacc (128*256); block 32 also zeros pz (128). Runs every call so the
// atomic accumulators start from zero on each graph replay.
// ---------------------------------------------------------------------------
__global__ __launch_bounds__(256) void prep_kernel(
    const float* __restrict__ W1, _Float16* __restrict__ W1p,
    float* __restrict__ pacc, float* __restrict__ pz)
{
    const int bid = blockIdx.x;
    const int tid = threadIdx.x;
    if (bid < 32) {
        const int g = bid * 256 + tid;          // [0, 8192)
        const int ct = g >> 9;
        const int ks = (g >> 6) & 7;
        const int l  = g & 63;
        const int k0 = ks * 32 + (l >> 4) * 8;
        const int col = ct * 16 + (l & 15);
        half8 h;
        #pragma unroll
        for (int j = 0; j < 8; ++j) h[j] = (_Float16)W1[(k0 + j) * H + col];
        reinterpret_cast<half8*>(W1p)[g] = h;
    } else {
        pacc[(bid - 32) * 256 + tid] = 0.f;     // 128*256 = 32768 exactly
        if (bid == 32 && tid < BATCH) pz[tid] = 0.f;
    }
}

// ---------------------------------------------------------------------------
// FUSED kernel = r14 structure (best known) with in-wave 2-tile pipelining
// (T15 analog): each block owns TWO independent 32-row tiles; MFMA/epilogue
// of tile 1 can overlap epilogue/MFMA of tile 0 in the same barrier-free
// region (separate MFMA and VALU pipes co-schedule, m114). Staging issues
// both tiles' loads together for deeper memory ILP.
// All per-tile pieces byte-identical to r14's verified forms.
// Max-free softmax (|score| <= ||W2||_1+|b2| ~ 13, exp f32-safe).
// ---------------------------------------------------------------------------
__global__ __launch_bounds__(256, 4) void fused_kernel(
    const float* __restrict__ X, const _Float16* __restrict__ W1p,
    const float* __restrict__ b1, const float* __restrict__ W2,
    const float* __restrict__ b2, const int* __restrict__ offsets,
    float* __restrict__ pacc, float* __restrict__ pz)
{
    __shared__ __align__(16) _Float16 Xs[2][TROWS * H];   // 2 x 16 KB, swizzled
    __shared__ float sp[2][4][TROWS];
    __shared__ float scL[2][TROWS];
    __shared__ float accL[4][H];
    __shared__ float zLs[4];
    __shared__ int offL[BATCH];

    const int tid = threadIdx.x;
    const int wave = tid >> 6;
    const int lane = tid & 63;

    // XCD-chunked bijective swizzle (2048 % 8 == 0)
    const int bid = (int)(blockIdx.x & 7) * (NBLOCKS / 8) + (int)(blockIdx.x >> 3);
    const int t0a = bid * 64;          // tile 0 rows [t0a, t0a+32)
    const int t0b = t0a + TROWS;       // tile 1 rows [t0b, t0b+32)

    if (tid < BATCH) offL[tid] = offsets[tid];

    // ---- 1. stage BOTH tiles (64 rows, f32 -> f16, XOR-swizzled) ----
    {
        const float4* Xv = reinterpret_cast<const float4*>(X + (long long)t0a * H);
        #pragma unroll
        for (int i = 0; i < 8; ++i) {
            const int c = tid + i * 256;        // 2048 half8-chunks over 64 rows
            const int row = c >> 5;             // 0..63
            const int col8 = c & 31;
            float4 a  = Xv[row * 64 + col8 * 2];
            float4 bq = Xv[row * 64 + col8 * 2 + 1];
            half8 h;
            h[0] = (_Float16)a.x;  h[1] = (_Float16)a.y;
            h[2] = (_Float16)a.z;  h[3] = (_Float16)a.w;
            h[4] = (_Float16)bq.x; h[5] = (_Float16)bq.y;
            h[6] = (_Float16)bq.z; h[7] = (_Float16)bq.w;
            const int r = row & 31;
            const int byte = r * 512 + (col8 * 16 ^ ((r & 7) << 4));
            *reinterpret_cast<half8*>(
                reinterpret_cast<char*>(&Xs[row >> 5][0]) + byte) = h;
        }
    }
    __syncthreads();   // [barrier 1] Xs[0], Xs[1] + offL ready

    // ---- 2+3. MFMA + epilogue for both tiles, one barrier-free region ----
    float w2v[4], b1v[4];
    #pragma unroll
    for (int ctl = 0; ctl < 4; ++ctl) {
        const int col = wave * 64 + ctl * 16 + (lane & 15);
        w2v[ctl] = W2[col];
        b1v[ctl] = b1[col];
    }

    const half8* Bw = reinterpret_cast<const half8*>(W1p) + wave * 2048 + lane;

    #pragma unroll
    for (int tile = 0; tile < 2; ++tile) {
        const char* Xb = reinterpret_cast<const char*>(&Xs[tile][0]);

        floatx4 acc[2][4];
        #pragma unroll
        for (int rt = 0; rt < 2; ++rt)
            #pragma unroll
            for (int ctl = 0; ctl < 4; ++ctl)
                acc[rt][ctl] = (floatx4){0.f, 0.f, 0.f, 0.f};

        #pragma unroll 1
        for (int ks = 0; ks < 8; ++ks) {
            half8 bf0 = Bw[ks * 64];
            half8 bf1 = Bw[512 + ks * 64];
            half8 bf2 = Bw[1024 + ks * 64];
            half8 bf3 = Bw[1536 + ks * 64];
            half8 af[2];
            #pragma unroll
            for (int rt = 0; rt < 2; ++rt) {
                const int row = rt * 16 + (lane & 15);
                const int byte = row * 512 +
                    ((ks * 64 + (lane >> 4) * 16) ^ ((row & 7) << 4));
                af[rt] = *reinterpret_cast<const half8*>(Xb + byte);
            }
            #pragma unroll
            for (int rt = 0; rt < 2; ++rt) {
                acc[rt][0] = __builtin_amdgcn_mfma_f32_16x16x32_f16(af[rt], bf0, acc[rt][0], 0, 0, 0);
                acc[rt][1] = __builtin_amdgcn_mfma_f32_16x16x32_f16(af[rt], bf1, acc[rt][1], 0, 0, 0);
                acc[rt][2] = __builtin_amdgcn_mfma_f32_16x16x32_f16(af[rt], bf2, acc[rt][2], 0, 0, 0);
                acc[rt][3] = __builtin_amdgcn_mfma_f32_16x16x32_f16(af[rt], bf3, acc[rt][3], 0, 0, 0);
            }
        }

        // epilogue: tanh + W2 dot -> 16-lane reduce -> sp[tile]
        float sc[2][4];
        #pragma unroll
        for (int rt = 0; rt < 2; ++rt) {
            #pragma unroll
            for (int reg = 0; reg < 4; ++reg) {
                float s = 0.f;
                #pragma unroll
                for (int ctl = 0; ctl < 4; ++ctl) {
                    const float x = acc[rt][ctl][reg] + b1v[ctl];
                    const float t = 1.f - 2.f / (__expf(2.f * x) + 1.f);
                    s = fmaf(t, w2v[ctl], s);
                }
                sc[rt][reg] = s;
            }
        }
        #pragma unroll
        for (int off = 1; off < 16; off <<= 1)
            #pragma unroll
            for (int rt = 0; rt < 2; ++rt)
                #pragma unroll
                for (int reg = 0; reg < 4; ++reg)
                    sc[rt][reg] += __shfl_xor(sc[rt][reg], off);

        if ((lane & 15) == 0) {
            #pragma unroll
            for (int rt = 0; rt < 2; ++rt)
                #pragma unroll
                for (int reg = 0; reg < 4; ++reg)
                    sp[tile][wave][rt * 16 + (lane >> 4) * 4 + reg] = sc[rt][reg];
        }
    }
    __syncthreads();   // [barrier 2] sp[0], sp[1] ready
    if (tid < 64) {
        const int tile = tid >> 5;
        const int rr = tid & 31;
        scL[tile][rr] = __expf(sp[tile][0][rr] + sp[tile][1][rr] +
                               sp[tile][2][rr] + sp[tile][3][rr] + b2[0]);
    }
    __syncthreads();   // [barrier 3] scL ready

    // ---- 4. PV from LDS per tile; accL combine; per-block atomics ----
    #pragma unroll
    for (int tile = 0; tile < 2; ++tile) {
        const int t0 = tile ? t0b : t0a;
        const char* Xb = reinterpret_cast<const char*>(&Xs[tile][0]);

        int g_lo, g_hi;
        {
            int node = t0;
            if (node < offL[0]) g_lo = -1;
            else {
                int lo = 0, hi = BATCH - 1;
                while (lo < hi) { int mid = (lo + hi + 1) >> 1; if (offL[mid] <= node) lo = mid; else hi = mid - 1; }
                g_lo = lo;
            }
            node = t0 + TROWS - 1;
            if (node < offL[0]) g_hi = -1;
            else {
                int lo = 0, hi = BATCH - 1;
                while (lo < hi) { int mid = (lo + hi + 1) >> 1; if (offL[mid] <= node) lo = mid; else hi = mid - 1; }
                g_hi = lo;
            }
        }

        for (int g = (g_lo < 0 ? 0 : g_lo); g <= g_hi; ++g) {
            const int rs = max(t0, offL[g]);
            const int re = min(t0 + TROWS, (g == BATCH - 1) ? N_NODES : offL[g + 1]);

            float4 a4 = {0.f, 0.f, 0.f, 0.f};
            float z = 0.f;
            for (int i = rs + wave; i < re; i += 4) {
                const int r = i - t0;
                const float p = scL[tile][r];
                const int byte = r * 512 + ((((lane >> 1) ^ (r & 7))) << 4) + (lane & 1) * 8;
                half4 xv = *reinterpret_cast<const half4*>(Xb + byte);
                a4.x = fmaf(p, (float)xv[0], a4.x);
                a4.y = fmaf(p, (float)xv[1], a4.y);
                a4.z = fmaf(p, (float)xv[2], a4.z);
                a4.w = fmaf(p, (float)xv[3], a4.w);
                z += p;
            }
            reinterpret_cast<float4*>(&accL[wave][0])[lane] = a4;
            if (lane == 0) zLs[wave] = z;
            __syncthreads();
            const float v = accL[0][tid] + accL[1][tid] + accL[2][tid] + accL[3][tid];
            atomicAdd(&pacc[g * H + tid], v);
            if (tid == 0) atomicAdd(&pz[g], zLs[0] + zLs[1] + zLs[2] + zLs[3]);
            __syncthreads();   // accL reused by next gap / next tile
        }
    }
}

// ---------------------------------------------------------------------------
// Reduce: segment b = union of gaps [max(b-1,0), min(b+1,127)].
// out = sum(acc_g) / sum(z_g). 128 blocks x 256 threads.
// ---------------------------------------------------------------------------
__global__ __launch_bounds__(256) void reduce_kernel(
    const float* __restrict__ pacc, const float* __restrict__ pz,
    float* __restrict__ out)
{
    const int b = blockIdx.x;
    const int tid = threadIdx.x;
    const int g0 = (b == 0) ? 0 : b - 1;
    const int g1 = (b >= BATCH - 1) ? BATCH - 1 : b + 1;

    float r = 0.f, z = 0.f;
    for (int g = g0; g <= g1; ++g) {
        r += pacc[g * H + tid];
        z += pz[g];
    }
    out[b * H + tid] = r / z;
}

// ---------------------------------------------------------------------------
extern "C" void kernel_launch(void* const* d_in, const int* in_sizes, int n_in,
                              void* d_out, int out_size, void* d_ws, size_t ws_size,
                              hipStream_t stream)
{
    const float* X     = (const float*)d_in[0];
    const int* offs    = (const int*)d_in[1];   // int64 in ref -> int32 on device
    const float* W1    = (const float*)d_in[2];
    const float* b1    = (const float*)d_in[3];
    const float* W2    = (const float*)d_in[4];
    const float* b2    = (const float*)d_in[5];
    float* out         = (float*)d_out;

    // workspace layout (floats):
    //   [0, 32768)        pacc   (128 gaps x 256)
    //   [32768, 32896)    pz     (128)
    //   [32896, ...)      W1p    (65536 f16 = 128 KB)
    float* pacc   = (float*)d_ws;
    float* pz     = pacc + BATCH * H;
    _Float16* W1p = (_Float16*)(pz + BATCH);

    prep_kernel<<<160, 256, 0, stream>>>(W1, W1p, pacc, pz);
    fused_kernel<<<NBLOCKS, 256, 0, stream>>>(X, W1p, b1, W2, b2, offs, pacc, pz);
    reduce_kernel<<<BATCH, 256, 0, stream>>>(pacc, pz, out);
}

// Round 19
// 61.545 us; speedup vs baseline: 1.1012x; 1.0593x over previous
//
#include <hip/hip_runtime.h>
#include <hip/hip_bf16.h>

#define N_NODES 131072
#define BATCH 128
#define H 256
#define TROWS 32
#define NTILES (N_NODES / TROWS)   // 4096 tiles of 32 rows

typedef _Float16 half8 __attribute__((ext_vector_type(8)));
typedef _Float16 half4 __attribute__((ext_vector_type(4)));
typedef float floatx4 __attribute__((ext_vector_type(4)));

// ---------------------------------------------------------------------------
// Prep: blocks 0..31 pack W1 into MFMA fragment order (f16); blocks 32..159
// zero pacc (128*256); block 32 also zeros pz (128). Runs every call so the
// atomic accumulators start from zero on each graph replay.
// ---------------------------------------------------------------------------
__global__ __launch_bounds__(256) void prep_kernel(
    const float* __restrict__ W1, _Float16* __restrict__ W1p,
    float* __restrict__ pacc, float* __restrict__ pz)
{
    const int bid = blockIdx.x;
    const int tid = threadIdx.x;
    if (bid < 32) {
        const int g = bid * 256 + tid;          // [0, 8192)
        const int ct = g >> 9;
        const int ks = (g >> 6) & 7;
        const int l  = g & 63;
        const int k0 = ks * 32 + (l >> 4) * 8;
        const int col = ct * 16 + (l & 15);
        half8 h;
        #pragma unroll
        for (int j = 0; j < 8; ++j) h[j] = (_Float16)W1[(k0 + j) * H + col];
        reinterpret_cast<half8*>(W1p)[g] = h;
    } else {
        pacc[(bid - 32) * 256 + tid] = 0.f;     // 128*256 = 32768 exactly
        if (bid == 32 && tid < BATCH) pz[tid] = 0.f;
    }
}

// ---------------------------------------------------------------------------
// FUSED kernel — r14 configuration (best measured: 61.0 us), restored.
// One 32-row tile per block; wave w owns col-tiles [4w,4w+4); X staged
// f32->f16 into XOR-swizzled LDS; MFMA (unroll-1 ks loop); tanh/W2 epilogue
// with 16-lane shfl + sp[] cross-wave combine; exp -> scL; PV from LDS with
// accL combine and per-block atomics per gap. Micro-fix vs r14: the trailing
// per-gap barrier only runs when another gap follows (block-uniform cond).
// Max-free softmax (|score| <= ||W2||_1+|b2| ~ 13, exp f32-safe).
// Plateau note: 12 structural variants (r7-r18) all land 61-68us with no
// pipe >40% — latency-chain-bound; this is the best-known configuration.
// ---------------------------------------------------------------------------
__global__ __launch_bounds__(256, 7) void fused_kernel(
    const float* __restrict__ X, const _Float16* __restrict__ W1p,
    const float* __restrict__ b1, const float* __restrict__ W2,
    const float* __restrict__ b2, const int* __restrict__ offsets,
    float* __restrict__ pacc, float* __restrict__ pz)
{
    __shared__ __align__(16) _Float16 Xs[TROWS * H];   // 16 KB, swizzled
    __shared__ float sp[4][TROWS];
    __shared__ float scL[TROWS];
    __shared__ float accL[4][H];
    __shared__ float zLs[4];
    __shared__ int offL[BATCH];

    const int tid = threadIdx.x;
    const int wave = tid >> 6;
    const int lane = tid & 63;

    // XCD-chunked bijective swizzle (4096 % 8 == 0)
    const int bid = (int)(blockIdx.x & 7) * (NTILES / 8) + (int)(blockIdx.x >> 3);
    const int t0 = bid * TROWS;

    if (tid < BATCH) offL[tid] = offsets[tid];

    // ---- 1. stage X tile (32 rows x 256 cols, f32 -> f16, XOR-swizzled) ----
    {
        const float4* Xv = reinterpret_cast<const float4*>(X + (long long)t0 * H);
        #pragma unroll
        for (int i = 0; i < 4; ++i) {
            const int c = tid + i * 256;        // 1024 half8-chunks
            const int row = c >> 5;
            const int col8 = c & 31;
            float4 a  = Xv[row * 64 + col8 * 2];
            float4 bq = Xv[row * 64 + col8 * 2 + 1];
            half8 h;
            h[0] = (_Float16)a.x;  h[1] = (_Float16)a.y;
            h[2] = (_Float16)a.z;  h[3] = (_Float16)a.w;
            h[4] = (_Float16)bq.x; h[5] = (_Float16)bq.y;
            h[6] = (_Float16)bq.z; h[7] = (_Float16)bq.w;
            int byte = row * 512 + (col8 * 16 ^ ((row & 7) << 4));
            *reinterpret_cast<half8*>(reinterpret_cast<char*>(Xs) + byte) = h;
        }
    }
    __syncthreads();   // [barrier 1] Xs + offL ready

    // ---- 2. MFMA: wave w = col-tiles [4w,4w+4), rows = 2 row-tiles ----
    floatx4 acc[2][4];
    #pragma unroll
    for (int rt = 0; rt < 2; ++rt)
        #pragma unroll
        for (int ctl = 0; ctl < 4; ++ctl)
            acc[rt][ctl] = (floatx4){0.f, 0.f, 0.f, 0.f};

    const half8* Bw = reinterpret_cast<const half8*>(W1p) + wave * 2048 + lane;

    #pragma unroll 1
    for (int ks = 0; ks < 8; ++ks) {
        half8 bf0 = Bw[ks * 64];
        half8 bf1 = Bw[512 + ks * 64];
        half8 bf2 = Bw[1024 + ks * 64];
        half8 bf3 = Bw[1536 + ks * 64];
        half8 af[2];
        #pragma unroll
        for (int rt = 0; rt < 2; ++rt) {
            const int row = rt * 16 + (lane & 15);
            const int byte = row * 512 +
                ((ks * 64 + (lane >> 4) * 16) ^ ((row & 7) << 4));
            af[rt] = *reinterpret_cast<const half8*>(
                reinterpret_cast<const char*>(Xs) + byte);
        }
        #pragma unroll
        for (int rt = 0; rt < 2; ++rt) {
            acc[rt][0] = __builtin_amdgcn_mfma_f32_16x16x32_f16(af[rt], bf0, acc[rt][0], 0, 0, 0);
            acc[rt][1] = __builtin_amdgcn_mfma_f32_16x16x32_f16(af[rt], bf1, acc[rt][1], 0, 0, 0);
            acc[rt][2] = __builtin_amdgcn_mfma_f32_16x16x32_f16(af[rt], bf2, acc[rt][2], 0, 0, 0);
            acc[rt][3] = __builtin_amdgcn_mfma_f32_16x16x32_f16(af[rt], bf3, acc[rt][3], 0, 0, 0);
        }
    }

    // ---- 3. epilogue: tanh + W2 dot -> 16-lane reduce -> sp -> exp ----
    float w2v[4], b1v[4];
    #pragma unroll
    for (int ctl = 0; ctl < 4; ++ctl) {
        const int col = wave * 64 + ctl * 16 + (lane & 15);
        w2v[ctl] = W2[col];
        b1v[ctl] = b1[col];
    }

    float sc[2][4];
    #pragma unroll
    for (int rt = 0; rt < 2; ++rt) {
        #pragma unroll
        for (int reg = 0; reg < 4; ++reg) {
            float s = 0.f;
            #pragma unroll
            for (int ctl = 0; ctl < 4; ++ctl) {
                const float x = acc[rt][ctl][reg] + b1v[ctl];
                const float t = 1.f - 2.f / (__expf(2.f * x) + 1.f);
                s = fmaf(t, w2v[ctl], s);
            }
            sc[rt][reg] = s;
        }
    }
    #pragma unroll
    for (int off = 1; off < 16; off <<= 1)
        #pragma unroll
        for (int rt = 0; rt < 2; ++rt)
            #pragma unroll
            for (int reg = 0; reg < 4; ++reg)
                sc[rt][reg] += __shfl_xor(sc[rt][reg], off);

    if ((lane & 15) == 0) {
        #pragma unroll
        for (int rt = 0; rt < 2; ++rt)
            #pragma unroll
            for (int reg = 0; reg < 4; ++reg)
                sp[wave][rt * 16 + (lane >> 4) * 4 + reg] = sc[rt][reg];
    }
    __syncthreads();   // [barrier 2] sp ready
    if (tid < TROWS)
        scL[tid] = __expf(sp[0][tid] + sp[1][tid] + sp[2][tid] + sp[3][tid] + b2[0]);
    __syncthreads();   // [barrier 3] scL ready

    // ---- 4. PV from LDS; accL combine; per-block atomics per gap ----
    int g_lo, g_hi;
    {
        int node = t0;
        if (node < offL[0]) g_lo = -1;
        else {
            int lo = 0, hi = BATCH - 1;
            while (lo < hi) { int mid = (lo + hi + 1) >> 1; if (offL[mid] <= node) lo = mid; else hi = mid - 1; }
            g_lo = lo;
        }
        node = t0 + TROWS - 1;
        if (node < offL[0]) g_hi = -1;
        else {
            int lo = 0, hi = BATCH - 1;
            while (lo < hi) { int mid = (lo + hi + 1) >> 1; if (offL[mid] <= node) lo = mid; else hi = mid - 1; }
            g_hi = lo;
        }
    }

    for (int g = (g_lo < 0 ? 0 : g_lo); g <= g_hi; ++g) {
        const int rs = max(t0, offL[g]);
        const int re = min(t0 + TROWS, (g == BATCH - 1) ? N_NODES : offL[g + 1]);

        float4 a4 = {0.f, 0.f, 0.f, 0.f};
        float z = 0.f;
        for (int i = rs + wave; i < re; i += 4) {
            const int r = i - t0;
            const float p = scL[r];
            const int byte = r * 512 + ((((lane >> 1) ^ (r & 7))) << 4) + (lane & 1) * 8;
            half4 xv = *reinterpret_cast<const half4*>(
                reinterpret_cast<const char*>(Xs) + byte);
            a4.x = fmaf(p, (float)xv[0], a4.x);
            a4.y = fmaf(p, (float)xv[1], a4.y);
            a4.z = fmaf(p, (float)xv[2], a4.z);
            a4.w = fmaf(p, (float)xv[3], a4.w);
            z += p;
        }
        reinterpret_cast<float4*>(&accL[wave][0])[lane] = a4;
        if (lane == 0) zLs[wave] = z;
        __syncthreads();
        const float v = accL[0][tid] + accL[1][tid] + accL[2][tid] + accL[3][tid];
        atomicAdd(&pacc[g * H + tid], v);
        if (tid == 0) atomicAdd(&pz[g], zLs[0] + zLs[1] + zLs[2] + zLs[3]);
        if (g < g_hi) __syncthreads();   // accL reuse fence (block-uniform cond)
    }
}

// ---------------------------------------------------------------------------
// Reduce: segment b = union of gaps [max(b-1,0), min(b+1,127)].
// out = sum(acc_g) / sum(z_g). 128 blocks x 256 threads.
// ---------------------------------------------------------------------------
__global__ __launch_bounds__(256) void reduce_kernel(
    const float* __restrict__ pacc, const float* __restrict__ pz,
    float* __restrict__ out)
{
    const int b = blockIdx.x;
    const int tid = threadIdx.x;
    const int g0 = (b == 0) ? 0 : b - 1;
    const int g1 = (b >= BATCH - 1) ? BATCH - 1 : b + 1;

    float r = 0.f, z = 0.f;
    for (int g = g0; g <= g1; ++g) {
        r += pacc[g * H + tid];
        z += pz[g];
    }
    out[b * H + tid] = r / z;
}

// ---------------------------------------------------------------------------
extern "C" void kernel_launch(void* const* d_in, const int* in_sizes, int n_in,
                              void* d_out, int out_size, void* d_ws, size_t ws_size,
                              hipStream_t stream)
{
    const float* X     = (const float*)d_in[0];
    const int* offs    = (const int*)d_in[1];   // int64 in ref -> int32 on device
    const float* W1    = (const float*)d_in[2];
    const float* b1    = (const float*)d_in[3];
    const float* W2    = (const float*)d_in[4];
    const float* b2    = (const float*)d_in[5];
    float* out         = (float*)d_out;

    // workspace layout (floats):
    //   [0, 32768)        pacc   (128 gaps x 256)
    //   [32768, 32896)    pz     (128)
    //   [32896, ...)      W1p    (65536 f16 = 128 KB)
    float* pacc   = (float*)d_ws;
    float* pz     = pacc + BATCH * H;
    _Float16* W1p = (_Float16*)(pz + BATCH);

    prep_kernel<<<160, 256, 0, stream>>>(W1, W1p, pacc, pz);
    fused_kernel<<<NTILES, 256, 0, stream>>>(X, W1p, b1, W2, b2, offs, pacc, pz);
    reduce_kernel<<<BATCH, 256, 0, stream>>>(pacc, pz, out);
}

// Round 21
// 60.578 us; speedup vs baseline: 1.1188x; 1.0160x over previous
//
#include <hip/hip_runtime.h>
#include <hip/hip_bf16.h>

#define N_NODES 131072
#define BATCH 128
#define H 256
#define TROWS 32
#define NTILES (N_NODES / TROWS)   // 4096 tiles of 32 rows

typedef _Float16 half8 __attribute__((ext_vector_type(8)));
typedef _Float16 half4 __attribute__((ext_vector_type(4)));
typedef __fp16 fp16x2 __attribute__((ext_vector_type(2)));   // cvt_pkrtz native type
typedef float floatx4 __attribute__((ext_vector_type(4)));

// ---------------------------------------------------------------------------
// Prep: blocks 0..31 pack W1 into MFMA fragment order (f16); blocks 32..159
// zero pacc (128*256); block 32 also zeros pz (128). Runs every call so the
// atomic accumulators start from zero on each graph replay.
// ---------------------------------------------------------------------------
__global__ __launch_bounds__(256) void prep_kernel(
    const float* __restrict__ W1, _Float16* __restrict__ W1p,
    float* __restrict__ pacc, float* __restrict__ pz)
{
    const int bid = blockIdx.x;
    const int tid = threadIdx.x;
    if (bid < 32) {
        const int g = bid * 256 + tid;          // [0, 8192)
        const int ct = g >> 9;
        const int ks = (g >> 6) & 7;
        const int l  = g & 63;
        const int k0 = ks * 32 + (l >> 4) * 8;
        const int col = ct * 16 + (l & 15);
        half8 h;
        #pragma unroll
        for (int j = 0; j < 8; ++j) h[j] = (_Float16)W1[(k0 + j) * H + col];
        reinterpret_cast<half8*>(W1p)[g] = h;
    } else {
        pacc[(bid - 32) * 256 + tid] = 0.f;     // 128*256 = 32768 exactly
        if (bid == 32 && tid < BATCH) pz[tid] = 0.f;
    }
}

// ---------------------------------------------------------------------------
// FUSED kernel — r14 structure (best measured: 61.0us) + VALU-diet:
//   (1) tanh: 2/(e+1) via v_rcp_f32 (__builtin_amdgcn_rcpf) instead of the
//       precise-division sequence (~10-15 VALU instr each, x32 per thread —
//       the largest single VALU term; VALUBusy=36% is the top counter).
//   (2) staging f32->f16 via packed v_cvt_pkrtz (16 instr vs 32 scalar cvt).
// Everything else byte-identical to the r19-verified kernel.
// Max-free softmax (|score| <= ||W2||_1+|b2| ~ 13, exp f32-safe).
// ---------------------------------------------------------------------------
__global__ __launch_bounds__(256, 7) void fused_kernel(
    const float* __restrict__ X, const _Float16* __restrict__ W1p,
    const float* __restrict__ b1, const float* __restrict__ W2,
    const float* __restrict__ b2, const int* __restrict__ offsets,
    float* __restrict__ pacc, float* __restrict__ pz)
{
    __shared__ __align__(16) _Float16 Xs[TROWS * H];   // 16 KB, swizzled
    __shared__ float sp[4][TROWS];
    __shared__ float scL[TROWS];
    __shared__ float accL[4][H];
    __shared__ float zLs[4];
    __shared__ int offL[BATCH];

    const int tid = threadIdx.x;
    const int wave = tid >> 6;
    const int lane = tid & 63;

    // XCD-chunked bijective swizzle (4096 % 8 == 0)
    const int bid = (int)(blockIdx.x & 7) * (NTILES / 8) + (int)(blockIdx.x >> 3);
    const int t0 = bid * TROWS;

    if (tid < BATCH) offL[tid] = offsets[tid];

    // ---- 1. stage X tile (f32 -> f16 via pk-cvt, XOR-swizzled) ----
    {
        const float4* Xv = reinterpret_cast<const float4*>(X + (long long)t0 * H);
        #pragma unroll
        for (int i = 0; i < 4; ++i) {
            const int c = tid + i * 256;        // 1024 half8-chunks
            const int row = c >> 5;
            const int col8 = c & 31;
            float4 a  = Xv[row * 64 + col8 * 2];
            float4 bq = Xv[row * 64 + col8 * 2 + 1];
            fp16x2 q0 = __builtin_amdgcn_cvt_pkrtz(a.x,  a.y);
            fp16x2 q1 = __builtin_amdgcn_cvt_pkrtz(a.z,  a.w);
            fp16x2 q2 = __builtin_amdgcn_cvt_pkrtz(bq.x, bq.y);
            fp16x2 q3 = __builtin_amdgcn_cvt_pkrtz(bq.z, bq.w);
            half8 h;
            h[0] = (_Float16)q0[0]; h[1] = (_Float16)q0[1];
            h[2] = (_Float16)q1[0]; h[3] = (_Float16)q1[1];
            h[4] = (_Float16)q2[0]; h[5] = (_Float16)q2[1];
            h[6] = (_Float16)q3[0]; h[7] = (_Float16)q3[1];
            int byte = row * 512 + (col8 * 16 ^ ((row & 7) << 4));
            *reinterpret_cast<half8*>(reinterpret_cast<char*>(Xs) + byte) = h;
        }
    }
    __syncthreads();   // [barrier 1] Xs + offL ready

    // ---- 2. MFMA: wave w = col-tiles [4w,4w+4), rows = 2 row-tiles ----
    floatx4 acc[2][4];
    #pragma unroll
    for (int rt = 0; rt < 2; ++rt)
        #pragma unroll
        for (int ctl = 0; ctl < 4; ++ctl)
            acc[rt][ctl] = (floatx4){0.f, 0.f, 0.f, 0.f};

    const half8* Bw = reinterpret_cast<const half8*>(W1p) + wave * 2048 + lane;

    #pragma unroll 1
    for (int ks = 0; ks < 8; ++ks) {
        half8 bf0 = Bw[ks * 64];
        half8 bf1 = Bw[512 + ks * 64];
        half8 bf2 = Bw[1024 + ks * 64];
        half8 bf3 = Bw[1536 + ks * 64];
        half8 af[2];
        #pragma unroll
        for (int rt = 0; rt < 2; ++rt) {
            const int row = rt * 16 + (lane & 15);
            const int byte = row * 512 +
                ((ks * 64 + (lane >> 4) * 16) ^ ((row & 7) << 4));
            af[rt] = *reinterpret_cast<const half8*>(
                reinterpret_cast<const char*>(Xs) + byte);
        }
        #pragma unroll
        for (int rt = 0; rt < 2; ++rt) {
            acc[rt][0] = __builtin_amdgcn_mfma_f32_16x16x32_f16(af[rt], bf0, acc[rt][0], 0, 0, 0);
            acc[rt][1] = __builtin_amdgcn_mfma_f32_16x16x32_f16(af[rt], bf1, acc[rt][1], 0, 0, 0);
            acc[rt][2] = __builtin_amdgcn_mfma_f32_16x16x32_f16(af[rt], bf2, acc[rt][2], 0, 0, 0);
            acc[rt][3] = __builtin_amdgcn_mfma_f32_16x16x32_f16(af[rt], bf3, acc[rt][3], 0, 0, 0);
        }
    }

    // ---- 3. epilogue: tanh (rcp-form) + W2 dot -> 16-lane reduce -> exp ----
    float w2v[4], b1v[4];
    #pragma unroll
    for (int ctl = 0; ctl < 4; ++ctl) {
        const int col = wave * 64 + ctl * 16 + (lane & 15);
        w2v[ctl] = W2[col];
        b1v[ctl] = b1[col];
    }

    float sc[2][4];
    #pragma unroll
    for (int rt = 0; rt < 2; ++rt) {
        #pragma unroll
        for (int reg = 0; reg < 4; ++reg) {
            float s = 0.f;
            #pragma unroll
            for (int ctl = 0; ctl < 4; ++ctl) {
                const float x = acc[rt][ctl][reg] + b1v[ctl];
                const float e = __expf(2.f * x);
                const float t = 1.f - 2.f * __builtin_amdgcn_rcpf(e + 1.f);
                s = fmaf(t, w2v[ctl], s);
            }
            sc[rt][reg] = s;
        }
    }
    #pragma unroll
    for (int off = 1; off < 16; off <<= 1)
        #pragma unroll
        for (int rt = 0; rt < 2; ++rt)
            #pragma unroll
            for (int reg = 0; reg < 4; ++reg)
                sc[rt][reg] += __shfl_xor(sc[rt][reg], off);

    if ((lane & 15) == 0) {
        #pragma unroll
        for (int rt = 0; rt < 2; ++rt)
            #pragma unroll
            for (int reg = 0; reg < 4; ++reg)
                sp[wave][rt * 16 + (lane >> 4) * 4 + reg] = sc[rt][reg];
    }
    __syncthreads();   // [barrier 2] sp ready
    if (tid < TROWS)
        scL[tid] = __expf(sp[0][tid] + sp[1][tid] + sp[2][tid] + sp[3][tid] + b2[0]);
    __syncthreads();   // [barrier 3] scL ready

    // ---- 4. PV from LDS; accL combine; per-block atomics per gap ----
    int g_lo, g_hi;
    {
        int node = t0;
        if (node < offL[0]) g_lo = -1;
        else {
            int lo = 0, hi = BATCH - 1;
            while (lo < hi) { int mid = (lo + hi + 1) >> 1; if (offL[mid] <= node) lo = mid; else hi = mid - 1; }
            g_lo = lo;
        }
        node = t0 + TROWS - 1;
        if (node < offL[0]) g_hi = -1;
        else {
            int lo = 0, hi = BATCH - 1;
            while (lo < hi) { int mid = (lo + hi + 1) >> 1; if (offL[mid] <= node) lo = mid; else hi = mid - 1; }
            g_hi = lo;
        }
    }

    for (int g = (g_lo < 0 ? 0 : g_lo); g <= g_hi; ++g) {
        const int rs = max(t0, offL[g]);
        const int re = min(t0 + TROWS, (g == BATCH - 1) ? N_NODES : offL[g + 1]);

        float4 a4 = {0.f, 0.f, 0.f, 0.f};
        float z = 0.f;
        for (int i = rs + wave; i < re; i += 4) {
            const int r = i - t0;
            const float p = scL[r];
            const int byte = r * 512 + ((((lane >> 1) ^ (r & 7))) << 4) + (lane & 1) * 8;
            half4 xv = *reinterpret_cast<const half4*>(
                reinterpret_cast<const char*>(Xs) + byte);
            a4.x = fmaf(p, (float)xv[0], a4.x);
            a4.y = fmaf(p, (float)xv[1], a4.y);
            a4.z = fmaf(p, (float)xv[2], a4.z);
            a4.w = fmaf(p, (float)xv[3], a4.w);
            z += p;
        }
        reinterpret_cast<float4*>(&accL[wave][0])[lane] = a4;
        if (lane == 0) zLs[wave] = z;
        __syncthreads();
        const float v = accL[0][tid] + accL[1][tid] + accL[2][tid] + accL[3][tid];
        atomicAdd(&pacc[g * H + tid], v);
        if (tid == 0) atomicAdd(&pz[g], zLs[0] + zLs[1] + zLs[2] + zLs[3]);
        if (g < g_hi) __syncthreads();   // accL reuse fence (block-uniform cond)
    }
}

// ---------------------------------------------------------------------------
// Reduce: segment b = union of gaps [max(b-1,0), min(b+1,127)].
// out = sum(acc_g) / sum(z_g). 128 blocks x 256 threads.
// ---------------------------------------------------------------------------
__global__ __launch_bounds__(256) void reduce_kernel(
    const float* __restrict__ pacc, const float* __restrict__ pz,
    float* __restrict__ out)
{
    const int b = blockIdx.x;
    const int tid = threadIdx.x;
    const int g0 = (b == 0) ? 0 : b - 1;
    const int g1 = (b >= BATCH - 1) ? BATCH - 1 : b + 1;

    float r = 0.f, z = 0.f;
    for (int g = g0; g <= g1; ++g) {
        r += pacc[g * H + tid];
        z += pz[g];
    }
    out[b * H + tid] = r / z;
}

// ---------------------------------------------------------------------------
extern "C" void kernel_launch(void* const* d_in, const int* in_sizes, int n_in,
                              void* d_out, int out_size, void* d_ws, size_t ws_size,
                              hipStream_t stream)
{
    const float* X     = (const float*)d_in[0];
    const int* offs    = (const int*)d_in[1];   // int64 in ref -> int32 on device
    const float* W1    = (const float*)d_in[2];
    const float* b1    = (const float*)d_in[3];
    const float* W2    = (const float*)d_in[4];
    const float* b2    = (const float*)d_in[5];
    float* out         = (float*)d_out;

    // workspace layout (floats):
    //   [0, 32768)        pacc   (128 gaps x 256)
    //   [32768, 32896)    pz     (128)
    //   [32896, ...)      W1p    (65536 f16 = 128 KB)
    float* pacc   = (float*)d_ws;
    float* pz     = pacc + BATCH * H;
    _Float16* W1p = (_Float16*)(pz + BATCH);

    prep_kernel<<<160, 256, 0, stream>>>(W1, W1p, pacc, pz);
    fused_kernel<<<NTILES, 256, 0, stream>>>(X, W1p, b1, W2, b2, offs, pacc, pz);
    reduce_kernel<<<BATCH, 256, 0, stream>>>(pacc, pz, out);
}

// Round 22
// 56.838 us; speedup vs baseline: 1.1924x; 1.0658x over previous
//
#include <hip/hip_runtime.h>
#include <hip/hip_bf16.h>

#define N_NODES 131072
#define BATCH 128
#define H 256
#define TROWS 32
#define NTILES (N_NODES / TROWS)   // 4096 tiles of 32 rows
#define NSUB 8                     // sub-slots per gap accumulator

typedef _Float16 half8 __attribute__((ext_vector_type(8)));
typedef _Float16 half4 __attribute__((ext_vector_type(4)));
typedef __fp16 fp16x2 __attribute__((ext_vector_type(2)));   // cvt_pkrtz native type
typedef float floatx4 __attribute__((ext_vector_type(4)));

// ---------------------------------------------------------------------------
// Prep: blocks 0..31 pack W1 into MFMA fragment order (f16); blocks 32..159
// zero pacc (128 gaps x 8 subs x 256 = 262144 floats; 2048 floats per block);
// block 32 also zeros pz (128x8=1024). Runs every call (graph-replay safe).
// ---------------------------------------------------------------------------
__global__ __launch_bounds__(256) void prep_kernel(
    const float* __restrict__ W1, _Float16* __restrict__ W1p,
    float* __restrict__ pacc, float* __restrict__ pz)
{
    const int bid = blockIdx.x;
    const int tid = threadIdx.x;
    if (bid < 32) {
        const int g = bid * 256 + tid;          // [0, 8192)
        const int ct = g >> 9;
        const int ks = (g >> 6) & 7;
        const int l  = g & 63;
        const int k0 = ks * 32 + (l >> 4) * 8;
        const int col = ct * 16 + (l & 15);
        half8 h;
        #pragma unroll
        for (int j = 0; j < 8; ++j) h[j] = (_Float16)W1[(k0 + j) * H + col];
        reinterpret_cast<half8*>(W1p)[g] = h;
    } else {
        const int base = (bid - 32) * 2048 + tid * 8;   // 128 blocks x 2048
        float4* p = reinterpret_cast<float4*>(&pacc[base]);
        p[0] = (float4){0.f, 0.f, 0.f, 0.f};
        p[1] = (float4){0.f, 0.f, 0.f, 0.f};
        if (bid == 32) {
            float4* q = reinterpret_cast<float4*>(&pz[tid * 4]);
            q[0] = (float4){0.f, 0.f, 0.f, 0.f};
        }
    }
}

// ---------------------------------------------------------------------------
// FUSED kernel — r21 structure (best measured: 60.6us), with 8-way
// sub-slotted accumulators: block adds into pacc[gap][bid&7][*] so each
// output dword sees ~4 same-address L2 RMWs instead of ~32 (XCD-swizzled
// bids of one gap are consecutive -> subs cycle 0-7). Tests the last
// unfalsified theory: atomic-retire serialization on the block tail.
// Everything else byte-identical to the r21-verified kernel.
// Max-free softmax (|score| <= ||W2||_1+|b2| ~ 13, exp f32-safe).
// ---------------------------------------------------------------------------
__global__ __launch_bounds__(256, 7) void fused_kernel(
    const float* __restrict__ X, const _Float16* __restrict__ W1p,
    const float* __restrict__ b1, const float* __restrict__ W2,
    const float* __restrict__ b2, const int* __restrict__ offsets,
    float* __restrict__ pacc, float* __restrict__ pz)
{
    __shared__ __align__(16) _Float16 Xs[TROWS * H];   // 16 KB, swizzled
    __shared__ float sp[4][TROWS];
    __shared__ float scL[TROWS];
    __shared__ float accL[4][H];
    __shared__ float zLs[4];
    __shared__ int offL[BATCH];

    const int tid = threadIdx.x;
    const int wave = tid >> 6;
    const int lane = tid & 63;

    // XCD-chunked bijective swizzle (4096 % 8 == 0)
    const int bid = (int)(blockIdx.x & 7) * (NTILES / 8) + (int)(blockIdx.x >> 3);
    const int t0 = bid * TROWS;
    const int sub = bid & (NSUB - 1);

    if (tid < BATCH) offL[tid] = offsets[tid];

    // ---- 1. stage X tile (f32 -> f16 via pk-cvt, XOR-swizzled) ----
    {
        const float4* Xv = reinterpret_cast<const float4*>(X + (long long)t0 * H);
        #pragma unroll
        for (int i = 0; i < 4; ++i) {
            const int c = tid + i * 256;        // 1024 half8-chunks
            const int row = c >> 5;
            const int col8 = c & 31;
            float4 a  = Xv[row * 64 + col8 * 2];
            float4 bq = Xv[row * 64 + col8 * 2 + 1];
            fp16x2 q0 = __builtin_amdgcn_cvt_pkrtz(a.x,  a.y);
            fp16x2 q1 = __builtin_amdgcn_cvt_pkrtz(a.z,  a.w);
            fp16x2 q2 = __builtin_amdgcn_cvt_pkrtz(bq.x, bq.y);
            fp16x2 q3 = __builtin_amdgcn_cvt_pkrtz(bq.z, bq.w);
            half8 h;
            h[0] = (_Float16)q0[0]; h[1] = (_Float16)q0[1];
            h[2] = (_Float16)q1[0]; h[3] = (_Float16)q1[1];
            h[4] = (_Float16)q2[0]; h[5] = (_Float16)q2[1];
            h[6] = (_Float16)q3[0]; h[7] = (_Float16)q3[1];
            int byte = row * 512 + (col8 * 16 ^ ((row & 7) << 4));
            *reinterpret_cast<half8*>(reinterpret_cast<char*>(Xs) + byte) = h;
        }
    }
    __syncthreads();   // [barrier 1] Xs + offL ready

    // ---- 2. MFMA: wave w = col-tiles [4w,4w+4), rows = 2 row-tiles ----
    floatx4 acc[2][4];
    #pragma unroll
    for (int rt = 0; rt < 2; ++rt)
        #pragma unroll
        for (int ctl = 0; ctl < 4; ++ctl)
            acc[rt][ctl] = (floatx4){0.f, 0.f, 0.f, 0.f};

    const half8* Bw = reinterpret_cast<const half8*>(W1p) + wave * 2048 + lane;

    #pragma unroll 1
    for (int ks = 0; ks < 8; ++ks) {
        half8 bf0 = Bw[ks * 64];
        half8 bf1 = Bw[512 + ks * 64];
        half8 bf2 = Bw[1024 + ks * 64];
        half8 bf3 = Bw[1536 + ks * 64];
        half8 af[2];
        #pragma unroll
        for (int rt = 0; rt < 2; ++rt) {
            const int row = rt * 16 + (lane & 15);
            const int byte = row * 512 +
                ((ks * 64 + (lane >> 4) * 16) ^ ((row & 7) << 4));
            af[rt] = *reinterpret_cast<const half8*>(
                reinterpret_cast<const char*>(Xs) + byte);
        }
        #pragma unroll
        for (int rt = 0; rt < 2; ++rt) {
            acc[rt][0] = __builtin_amdgcn_mfma_f32_16x16x32_f16(af[rt], bf0, acc[rt][0], 0, 0, 0);
            acc[rt][1] = __builtin_amdgcn_mfma_f32_16x16x32_f16(af[rt], bf1, acc[rt][1], 0, 0, 0);
            acc[rt][2] = __builtin_amdgcn_mfma_f32_16x16x32_f16(af[rt], bf2, acc[rt][2], 0, 0, 0);
            acc[rt][3] = __builtin_amdgcn_mfma_f32_16x16x32_f16(af[rt], bf3, acc[rt][3], 0, 0, 0);
        }
    }

    // ---- 3. epilogue: tanh (rcp-form) + W2 dot -> 16-lane reduce -> exp ----
    float w2v[4], b1v[4];
    #pragma unroll
    for (int ctl = 0; ctl < 4; ++ctl) {
        const int col = wave * 64 + ctl * 16 + (lane & 15);
        w2v[ctl] = W2[col];
        b1v[ctl] = b1[col];
    }

    float sc[2][4];
    #pragma unroll
    for (int rt = 0; rt < 2; ++rt) {
        #pragma unroll
        for (int reg = 0; reg < 4; ++reg) {
            float s = 0.f;
            #pragma unroll
            for (int ctl = 0; ctl < 4; ++ctl) {
                const float x = acc[rt][ctl][reg] + b1v[ctl];
                const float e = __expf(2.f * x);
                const float t = 1.f - 2.f * __builtin_amdgcn_rcpf(e + 1.f);
                s = fmaf(t, w2v[ctl], s);
            }
            sc[rt][reg] = s;
        }
    }
    #pragma unroll
    for (int off = 1; off < 16; off <<= 1)
        #pragma unroll
        for (int rt = 0; rt < 2; ++rt)
            #pragma unroll
            for (int reg = 0; reg < 4; ++reg)
                sc[rt][reg] += __shfl_xor(sc[rt][reg], off);

    if ((lane & 15) == 0) {
        #pragma unroll
        for (int rt = 0; rt < 2; ++rt)
            #pragma unroll
            for (int reg = 0; reg < 4; ++reg)
                sp[wave][rt * 16 + (lane >> 4) * 4 + reg] = sc[rt][reg];
    }
    __syncthreads();   // [barrier 2] sp ready
    if (tid < TROWS)
        scL[tid] = __expf(sp[0][tid] + sp[1][tid] + sp[2][tid] + sp[3][tid] + b2[0]);
    __syncthreads();   // [barrier 3] scL ready

    // ---- 4. PV from LDS; accL combine; sub-slotted atomics per gap ----
    int g_lo, g_hi;
    {
        int node = t0;
        if (node < offL[0]) g_lo = -1;
        else {
            int lo = 0, hi = BATCH - 1;
            while (lo < hi) { int mid = (lo + hi + 1) >> 1; if (offL[mid] <= node) lo = mid; else hi = mid - 1; }
            g_lo = lo;
        }
        node = t0 + TROWS - 1;
        if (node < offL[0]) g_hi = -1;
        else {
            int lo = 0, hi = BATCH - 1;
            while (lo < hi) { int mid = (lo + hi + 1) >> 1; if (offL[mid] <= node) lo = mid; else hi = mid - 1; }
            g_hi = lo;
        }
    }

    for (int g = (g_lo < 0 ? 0 : g_lo); g <= g_hi; ++g) {
        const int rs = max(t0, offL[g]);
        const int re = min(t0 + TROWS, (g == BATCH - 1) ? N_NODES : offL[g + 1]);

        float4 a4 = {0.f, 0.f, 0.f, 0.f};
        float z = 0.f;
        for (int i = rs + wave; i < re; i += 4) {
            const int r = i - t0;
            const float p = scL[r];
            const int byte = r * 512 + ((((lane >> 1) ^ (r & 7))) << 4) + (lane & 1) * 8;
            half4 xv = *reinterpret_cast<const half4*>(
                reinterpret_cast<const char*>(Xs) + byte);
            a4.x = fmaf(p, (float)xv[0], a4.x);
            a4.y = fmaf(p, (float)xv[1], a4.y);
            a4.z = fmaf(p, (float)xv[2], a4.z);
            a4.w = fmaf(p, (float)xv[3], a4.w);
            z += p;
        }
        reinterpret_cast<float4*>(&accL[wave][0])[lane] = a4;
        if (lane == 0) zLs[wave] = z;
        __syncthreads();
        const float v = accL[0][tid] + accL[1][tid] + accL[2][tid] + accL[3][tid];
        atomicAdd(&pacc[(g * NSUB + sub) * H + tid], v);
        if (tid == 0) atomicAdd(&pz[g * NSUB + sub], zLs[0] + zLs[1] + zLs[2] + zLs[3]);
        if (g < g_hi) __syncthreads();   // accL reuse fence (block-uniform cond)
    }
}

// ---------------------------------------------------------------------------
// Reduce: segment b = union of gaps [max(b-1,0), min(b+1,127)].
// out = sum over gaps & sub-slots / z. 128 blocks x 256 threads.
// ---------------------------------------------------------------------------
__global__ __launch_bounds__(256) void reduce_kernel(
    const float* __restrict__ pacc, const float* __restrict__ pz,
    float* __restrict__ out)
{
    const int b = blockIdx.x;
    const int tid = threadIdx.x;
    const int g0 = (b == 0) ? 0 : b - 1;
    const int g1 = (b >= BATCH - 1) ? BATCH - 1 : b + 1;

    float r = 0.f, z = 0.f;
    for (int g = g0; g <= g1; ++g) {
        #pragma unroll
        for (int s = 0; s < NSUB; ++s) {
            r += pacc[(g * NSUB + s) * H + tid];
            z += pz[g * NSUB + s];
        }
    }
    out[b * H + tid] = r / z;
}

// ---------------------------------------------------------------------------
extern "C" void kernel_launch(void* const* d_in, const int* in_sizes, int n_in,
                              void* d_out, int out_size, void* d_ws, size_t ws_size,
                              hipStream_t stream)
{
    const float* X     = (const float*)d_in[0];
    const int* offs    = (const int*)d_in[1];   // int64 in ref -> int32 on device
    const float* W1    = (const float*)d_in[2];
    const float* b1    = (const float*)d_in[3];
    const float* W2    = (const float*)d_in[4];
    const float* b2    = (const float*)d_in[5];
    float* out         = (float*)d_out;

    // workspace layout (floats):
    //   [0, 262144)           pacc   (128 gaps x 8 subs x 256)
    //   [262144, 263168)      pz     (128 x 8)
    //   [263168, ...)         W1p    (65536 f16 = 128 KB)
    float* pacc   = (float*)d_ws;
    float* pz     = pacc + BATCH * NSUB * H;
    _Float16* W1p = (_Float16*)(pz + BATCH * NSUB);

    prep_kernel<<<160, 256, 0, stream>>>(W1, W1p, pacc, pz);
    fused_kernel<<<NTILES, 256, 0, stream>>>(X, W1p, b1, W2, b2, offs, pacc, pz);
    reduce_kernel<<<BATCH, 256, 0, stream>>>(pacc, pz, out);
}